// Round 6
// baseline (499.078 us; speedup 1.0000x reference)
//
#include <hip/hip_runtime.h>
#include <stdint.h>

// ---------------------------------------------------------------------------
// Fused 2-layer tanh RNN + FC head for MI355X (gfx950).  Round 6.
//
// B=512,T=1024,I=32,H1=128,H2=64,C=10.  32 blocks x 512 threads (8 waves),
// 16 batch rows/block, whole serial T-loop in-block.
//
// ANTI-PHASE STRUCTURE (2 lgkm-only barriers per step):
//   phase A: l1 waves (0-3): read h1(t) frags, 8 rec-MFMA + 4 l2-input-proj
//            MFMA (ABSORBED: reuses the same b1 frags; z2-partials pass to
//            l2 waves point-to-point in D-layout, 1 ds op each), write partial.
//            l2 waves (4-7): tanh z2(prev) -> write h2 state.   [barrier B1]
//   phase B: l1: tanh z1 -> write h1(t+1); x-proj MFMA for t+1.
//            l2: read partial + h2 panel, 2 MFMA -> z2 kept in REGS.  [B0]
// This overlaps the three per-CU pipes (LDS ~450c, MFMA ~310c/SIMD,
// VALU ~400c) that barrier-lockstep was serializing (r1-r5 ~1100c/step).
// LDS traffic: 46 -> 38 KB/step (l2 no longer re-reads the h1 panel).
// amdgpu_waves_per_eu(2,2): pin occupancy target so the backend stops
// squeezing into 64 VGPRs (r4/r5 pathology).
// ---------------------------------------------------------------------------

typedef _Float16 f16x8 __attribute__((ext_vector_type(8)));
typedef float f32x4 __attribute__((ext_vector_type(4)));

#define MFMA_F16(A, B, C) __builtin_amdgcn_mfma_f32_16x16x32_f16((A), (B), (C), 0, 0, 0)

__device__ __forceinline__ float tanh_fast(float x) {
  // tanh(x) = 1 - 2/(1 + 2^(2x*log2e)); abs err ~1e-6.
  float t = __builtin_amdgcn_exp2f(x * 2.88539008177792681472f);
  return 1.0f - 2.0f * __builtin_amdgcn_rcpf(t + 1.0f);
}

__device__ __forceinline__ uint32_t pk16(float a, float b) {
  return __builtin_bit_cast(uint32_t, __builtin_amdgcn_cvt_pkrtz(a, b));
}

// LDS-only barrier: drain ds ops, rendezvous. Leaves global loads in flight.
__device__ __forceinline__ void sync_lds() {
  asm volatile("s_waitcnt lgkmcnt(0)\n\ts_barrier" ::: "memory");
}

__global__ __attribute__((amdgpu_waves_per_eu(2, 2))) __launch_bounds__(512)
void rnn_fused(
    const float* __restrict__ x,
    const float* __restrict__ Wih1, const float* __restrict__ Whh1,
    const float* __restrict__ bih1, const float* __restrict__ bhh1,
    const float* __restrict__ Wih2, const float* __restrict__ Whh2,
    const float* __restrict__ bih2, const float* __restrict__ bhh2,
    const float* __restrict__ Wfc,  const float* __restrict__ bfc,
    float* __restrict__ out)
{
  constexpr int T = 1024, I = 32, H1 = 128, H2 = 64, BB = 16;
  // Padded LDS row strides (conflict-free b128/b64): 272B (h1), 144B (h2).
  constexpr int R1 = 272, R2 = 144;
  constexpr int H1_0 = 0;            // h1 buf0: 16*272 = 4352
  constexpr int H1_1 = 4352;         // h1 buf1
  constexpr int H2B  = 8704;         // h2 state (single buffer): 16*144 = 2304
  constexpr int P2B  = 11008;        // z2 partials f32, 4 waves * 1KB = 4096
  constexpr int H2F  = 15104;        // final h2 f32: 16 rows * 256B = 4096
  __shared__ __align__(16) unsigned char smem[19200];

  const int tid  = threadIdx.x;
  const int w    = tid >> 6;      // wave 0..7
  const int lane = tid & 63;
  const int g    = lane >> 4;     // k-group 0..3
  const int n    = lane & 15;     // batch col 0..15
  const int b0   = blockIdx.x * BB;

  // ---- zero h1(0) (h2/P2 are fully written at t=0 before any read) ----
  {
    uint32_t* p = (uint32_t*)smem;
    for (int i = tid; i < 1088; i += 512) p[i] = 0u;   // H1[0]
  }

  auto cvt8 = [](const float* s) -> f16x8 {
    f32x4 a = *(const f32x4*)s;
    f32x4 b = *(const f32x4*)(s + 4);
    f16x8 r;
#pragma unroll
    for (int j = 0; j < 4; ++j) { r[j] = (_Float16)a[j]; r[4 + j] = (_Float16)b[j]; }
    return r;
  };

  // h1 B-frag read offsets (l1 waves): k = k4*32 + g*8.
  int roff1[4];
#pragma unroll
  for (int k4 = 0; k4 < 4; ++k4)
    roff1[k4] = n * R1 + k4 * 64 + g * 16;

  // z2-partial slot (point-to-point, lane-linear, conflict-free)
  const int poff = (w & 3) * 1024 + (g * 16 + n) * 16;

  auto tanh_pack = [&](const f32x4& a, uint32_t& lo, uint32_t& hi) {
    lo = pk16(tanh_fast(a[0]), tanh_fast(a[1]));
    hi = pk16(tanh_fast(a[2]), tanh_fast(a[3]));
  };

  __syncthreads();  // zero-init visible (once)

  const f32x4 zero = {0.f, 0.f, 0.f, 0.f};

  if (w < 4) {
    // ============ layer-1 wave: tiles {2w,2w+1} = ch 32w..32w+31, plus
    // ============ l2-input-projection for l2 tile w (ch2 16w..16w+15) =====
    f16x8 aU[2][4], aI1[2], aI2[4];
    f32x4 bias1[2], bias2v;
#pragma unroll
    for (int ti = 0; ti < 2; ++ti) {
      const int ch = (2 * w + ti) * 16 + n;
#pragma unroll
      for (int k4 = 0; k4 < 4; ++k4)
        aU[ti][k4] = cvt8(Whh1 + ch * H1 + k4 * 32 + g * 8);
      aI1[ti] = cvt8(Wih1 + ch * I + g * 8);
      const int cb = (2 * w + ti) * 16 + g * 4;
#pragma unroll
      for (int r = 0; r < 4; ++r) bias1[ti][r] = bih1[cb + r] + bhh1[cb + r];
    }
#pragma unroll
    for (int k4 = 0; k4 < 4; ++k4)
      aI2[k4] = cvt8(Wih2 + (16 * w + n) * H1 + k4 * 32 + g * 8);
#pragma unroll
    for (int r = 0; r < 4; ++r)
      bias2v[r] = bih2[16 * w + g * 4 + r] + bhh2[16 * w + g * 4 + r];

    int woff[2];
#pragma unroll
    for (int ti = 0; ti < 2; ++ti)
      woff[ti] = n * R1 + (2 * w + ti) * 32 + g * 8;

    const float* xp = x + (size_t)(b0 + n) * T * I + g * 8;
    f32x4 q0a = *(const f32x4*)(xp + 0 * I), q0b = *(const f32x4*)(xp + 0 * I + 4);
    f32x4 q1a = *(const f32x4*)(xp + 1 * I), q1b = *(const f32x4*)(xp + 1 * I + 4);
    f32x4 q2a = *(const f32x4*)(xp + 2 * I), q2b = *(const f32x4*)(xp + 2 * I + 4);
    f32x4 q3a = *(const f32x4*)(xp + 3 * I), q3b = *(const f32x4*)(xp + 3 * I + 4);

    auto pack_x = [&](const f32x4& a, const f32x4& b) -> f16x8 {
      union { uint32_t u[4]; f16x8 v; } tmp;
      tmp.u[0] = pk16(a[0], a[1]); tmp.u[1] = pk16(a[2], a[3]);
      tmp.u[2] = pk16(b[0], b[1]); tmp.u[3] = pk16(b[2], b[3]);
      return tmp.v;
    };

    // accI(0) = Wih1*x(0) + bias1
    f32x4 accI0, accI1;
    {
      f16x8 xf = pack_x(q0a, q0b);
      accI0 = MFMA_F16(aI1[0], xf, bias1[0]);
      accI1 = MFMA_F16(aI1[1], xf, bias1[1]);
    }

    auto stepL1 = [&](int t, int cur, f32x4& la, f32x4& lb,
                      const f32x4& pa, const f32x4& pb) {
      const char* H1c = (const char*)smem + (cur ? H1_1 : H1_0);
      char*       H1n = (char*)smem + (cur ? H1_0 : H1_1);
      // ---------- phase A: reads + all heavy MFMA ----------
      f16x8 b1k0 = *(const f16x8*)(H1c + roff1[0]);
      f16x8 b1k1 = *(const f16x8*)(H1c + roff1[1]);
      f16x8 b1k2 = *(const f16x8*)(H1c + roff1[2]);
      f16x8 b1k3 = *(const f16x8*)(H1c + roff1[3]);
      if (t + 4 < T) {  // x(t+4) into the just-consumed slot
        la = *(const f32x4*)(xp + (t + 4) * I);
        lb = *(const f32x4*)(xp + (t + 4) * I + 4);
      }
      // l2 input projection partial (must land in LDS before B1)
      f32x4 pA = MFMA_F16(aI2[0], b1k0, bias2v);
      f32x4 pB = MFMA_F16(aI2[1], b1k1, zero);
      pA = MFMA_F16(aI2[2], b1k2, pA);
      pB = MFMA_F16(aI2[3], b1k3, pB);
      // l1 recurrent chains (results needed only after B1, same wave)
      f32x4 aA0 = MFMA_F16(aU[0][0], b1k0, accI0);
      f32x4 aB0 = MFMA_F16(aU[0][2], b1k2, zero);
      f32x4 aA1 = MFMA_F16(aU[1][0], b1k0, accI1);
      f32x4 aB1 = MFMA_F16(aU[1][2], b1k2, zero);
      aA0 = MFMA_F16(aU[0][1], b1k1, aA0);
      aB0 = MFMA_F16(aU[0][3], b1k3, aB0);
      aA1 = MFMA_F16(aU[1][1], b1k1, aA1);
      aB1 = MFMA_F16(aU[1][3], b1k3, aB1);
      f32x4 part = pA + pB;
      *(f32x4*)((char*)smem + P2B + poff) = part;
      sync_lds();  // B1
      // ---------- phase B: activation + write + x-proj for t+1 ----------
      {
        f32x4 s0 = aA0 + aB0;
        uint32_t lo, hi;
        tanh_pack(s0, lo, hi);
        *(uint2*)(H1n + woff[0]) = make_uint2(lo, hi);
      }
      {
        f32x4 s1 = aA1 + aB1;
        uint32_t lo, hi;
        tanh_pack(s1, lo, hi);
        *(uint2*)(H1n + woff[1]) = make_uint2(lo, hi);
      }
      {
        f16x8 xf = pack_x(pa, pb);
        accI0 = MFMA_F16(aI1[0], xf, bias1[0]);
        accI1 = MFMA_F16(aI1[1], xf, bias1[1]);
      }
      sync_lds();  // B0
    };

    for (int t = 0; t < T; t += 4) {
      stepL1(t + 0, 0, q0a, q0b, q1a, q1b);
      stepL1(t + 1, 1, q1a, q1b, q2a, q2b);
      stepL1(t + 2, 0, q2a, q2b, q3a, q3b);
      stepL1(t + 3, 1, q3a, q3b, q0a, q0b);
    }
    // extra iteration t=1024: provides partial(1024) for the final l2 step.
    stepL1(T, 0, q0a, q0b, q1a, q1b);
  } else {
    // ============ layer-2 wave: tile j = w-4 (ch2 16j..16j+15) =============
    const int j = w - 4;
    f16x8 aR2[2];
#pragma unroll
    for (int k2 = 0; k2 < 2; ++k2)
      aR2[k2] = cvt8(Whh2 + (16 * j + n) * H2 + k2 * 32 + g * 8);

    int roff2[2];
#pragma unroll
    for (int k2 = 0; k2 < 2; ++k2)
      roff2[k2] = n * R2 + k2 * 64 + g * 16;
    const int woff2 = n * R2 + j * 32 + g * 8;
    const int poffr = j * 1024 + (g * 16 + n) * 16;

    f32x4 z2 = zero;  // z2(t-1) carried in registers; tanh deferred

    auto stepL2 = [&](int t) {
      // ---------- phase A: activation of z2(t-1) -> h2 state ----------
      {
        uint32_t lo, hi;
        tanh_pack(z2, lo, hi);   // t=0: tanh(0)=0 == initial h2 state
        *(uint2*)((char*)smem + H2B + woff2) = make_uint2(lo, hi);
      }
      sync_lds();  // B1
      // ---------- phase B: read partial + h2 panel, 2 MFMA ----------
      if (t > 0) {
        f32x4 part = *(const f32x4*)((char*)smem + P2B + poffr);
        f16x8 b2k0 = *(const f16x8*)((char*)smem + H2B + roff2[0]);
        f16x8 b2k1 = *(const f16x8*)((char*)smem + H2B + roff2[1]);
        z2 = MFMA_F16(aR2[0], b2k0, part);
        z2 = MFMA_F16(aR2[1], b2k1, z2);
      } else {
        z2 = zero;  // forces h2 state written at t=1 to stay zero (= h2_ref(-1))
      }
      sync_lds();  // B0
    };

    for (int t = 0; t < T; t += 4) {
      stepL2(t + 0);
      stepL2(t + 1);
      stepL2(t + 2);
      stepL2(t + 3);
    }
    stepL2(T);  // z2(1024) -> h2_ref(1023), kept in regs

    // final activation -> f32 h2f for the FC head
    {
      f32x4 hv;
#pragma unroll
      for (int r = 0; r < 4; ++r) hv[r] = tanh_fast(z2[r]);
      *(f32x4*)(smem + H2F + n * 256 + (16 * j + 4 * g) * 4) = hv;
    }
  }

  sync_lds();  // h2f visible (l1 waves arrive after their loop)

  // ---- FC head: logits[b][c] = b_fc[c] + sum_k h2f[b][k] * Wfc[c][k] ----
  if (tid < BB * 10) {
    const int b = tid / 10, c = tid % 10;
    const float* hrow = (const float*)(smem + H2F + b * 256);
    float acc = bfc[c];
#pragma unroll 8
    for (int k = 0; k < 64; ++k) acc += hrow[k] * Wfc[c * 64 + k];
    out[(size_t)(b0 + b) * 10 + c] = acc;
  }
}

extern "C" void kernel_launch(void* const* d_in, const int* in_sizes, int n_in,
                              void* d_out, int out_size, void* d_ws, size_t ws_size,
                              hipStream_t stream) {
  const float* x    = (const float*)d_in[0];
  const float* Wih1 = (const float*)d_in[1];
  const float* Whh1 = (const float*)d_in[2];
  const float* bih1 = (const float*)d_in[3];
  const float* bhh1 = (const float*)d_in[4];
  const float* Wih2 = (const float*)d_in[5];
  const float* Whh2 = (const float*)d_in[6];
  const float* bih2 = (const float*)d_in[7];
  const float* bhh2 = (const float*)d_in[8];
  const float* Wfc  = (const float*)d_in[9];
  const float* bfc  = (const float*)d_in[10];

  hipLaunchKernelGGL(rnn_fused, dim3(512 / 16), dim3(512), 0, stream,
                     x, Wih1, Whh1, bih1, bhh1, Wih2, Whh2, bih2, bhh2,
                     Wfc, bfc, (float*)d_out);
}

// Round 7
// 433.078 us; speedup vs baseline: 1.1524x; 1.1524x over previous
//
#include <hip/hip_runtime.h>
#include <stdint.h>

// ---------------------------------------------------------------------------
// Fused 2-layer tanh RNN + FC head for MI355X (gfx950).  Round 7.
//
// B=512,T=1024,I=32,H1=128,H2=64,C=10.
//
// KERNEL 1 (xw_pre, 256 blocks, all CUs): xw[b][t] = Wih1 x[b][t] + b_ih1 +
//   b_hh1, stored fp16 in MFMA C/D fragment layout (per batch-group, per t,
//   per M-tile, per lane: 4 f16 = 8B).  Fully parallel, ~40us.
// KERNEL 2 (rnn_rec, 32 blocks x 512 thr = 8 waves): r4 skeleton -- waves
//   0-3 layer-1 (32ch), waves 4-7 layer-2 (16ch, lagged 1), padded LDS rows
//   (272B/144B), ONE lgkm-only barrier per step.  l1's x-path replaced by
//   two 8B global loads of xw (dist-2 prefetch; vmcnt survives the barrier)
//   feeding the MFMA C-init directly:
//     - removes 32-VGPR x-queue (r4/r5's 64-VGPR squeeze -> spill remat),
//     - removes per-step pack_x VALU + 2 xproj MFMA,
//     - critical chain becomes ds_read -> 2 dep MFMA -> tanh -> write.
// Fallback (ws too small for 134MB xw): exact r4 path.
// ---------------------------------------------------------------------------

typedef _Float16 f16x8 __attribute__((ext_vector_type(8)));
typedef _Float16 f16x4 __attribute__((ext_vector_type(4)));
typedef float f32x4 __attribute__((ext_vector_type(4)));

#define MFMA_F16(A, B, C) __builtin_amdgcn_mfma_f32_16x16x32_f16((A), (B), (C), 0, 0, 0)

__device__ __forceinline__ float tanh_fast(float x) {
  float t = __builtin_amdgcn_exp2f(x * 2.88539008177792681472f);
  return 1.0f - 2.0f * __builtin_amdgcn_rcpf(t + 1.0f);
}

__device__ __forceinline__ uint32_t pk16(float a, float b) {
  return __builtin_bit_cast(uint32_t, __builtin_amdgcn_cvt_pkrtz(a, b));
}

__device__ __forceinline__ void sync_lds() {
  asm volatile("s_waitcnt lgkmcnt(0)\n\ts_barrier" ::: "memory");
}

__device__ __forceinline__ f16x8 cvt8w(const float* s) {
  f32x4 a = *(const f32x4*)s;
  f32x4 b = *(const f32x4*)(s + 4);
  f16x8 r;
#pragma unroll
  for (int j = 0; j < 4; ++j) { r[j] = (_Float16)a[j]; r[4 + j] = (_Float16)b[j]; }
  return r;
}

__device__ __forceinline__ f16x8 pack_x8(const f32x4& a, const f32x4& b) {
  union { uint32_t u[4]; f16x8 v; } tmp;
  tmp.u[0] = pk16(a[0], a[1]); tmp.u[1] = pk16(a[2], a[3]);
  tmp.u[2] = pk16(b[0], b[1]); tmp.u[3] = pk16(b[2], b[3]);
  return tmp.v;
}

// ============================ kernel 1: xw precompute ========================
// grid: 256 blocks x 256 thr.  block = (gb 0..31) x (t-chunk 0..7, 128 t).
// wave w covers 32 t.  xw uint2 index: ((gb*1024 + t)*8 + m)*64 + lane.
__global__ __launch_bounds__(256) void xw_pre(
    const float* __restrict__ x, const float* __restrict__ Wih1,
    const float* __restrict__ bih1, const float* __restrict__ bhh1,
    uint2* __restrict__ xw)
{
  const int tid  = threadIdx.x;
  const int w    = tid >> 6, lane = tid & 63;
  const int g    = lane >> 4, n = lane & 15;
  const int gb   = blockIdx.x >> 3;
  const int t0   = ((blockIdx.x & 7) << 7) + (w << 5);

  f16x8 aI[8];
  f32x4 bias[8];
#pragma unroll
  for (int m = 0; m < 8; ++m) {
    aI[m] = cvt8w(Wih1 + (m * 16 + n) * 32 + g * 8);
#pragma unroll
    for (int r = 0; r < 4; ++r)
      bias[m][r] = bih1[m * 16 + g * 4 + r] + bhh1[m * 16 + g * 4 + r];
  }

  const float* xp = x + ((size_t)(gb * 16 + n) * 1024 + t0) * 32 + g * 8;
  uint2* xo = xw + (size_t)(gb * 1024 + t0) * 512 + lane;

  f32x4 xa = *(const f32x4*)(xp);
  f32x4 xb = *(const f32x4*)(xp + 4);
  for (int tt = 0; tt < 32; ++tt) {
    f32x4 na, nb;
    if (tt < 31) {
      na = *(const f32x4*)(xp + (tt + 1) * 32);
      nb = *(const f32x4*)(xp + (tt + 1) * 32 + 4);
    }
    f16x8 xf = pack_x8(xa, xb);
#pragma unroll
    for (int m = 0; m < 8; ++m) {
      f32x4 d = MFMA_F16(aI[m], xf, bias[m]);
      xo[tt * 512 + m * 64] = make_uint2(pk16(d[0], d[1]), pk16(d[2], d[3]));
    }
    xa = na; xb = nb;
  }
}

// ============================ kernel 2: recurrence ===========================
template <bool USE_XW>
__global__ __attribute__((amdgpu_waves_per_eu(2, 2))) __launch_bounds__(512)
void rnn_rec(
    const float* __restrict__ x,
    const float* __restrict__ Wih1, const float* __restrict__ Whh1,
    const float* __restrict__ bih1, const float* __restrict__ bhh1,
    const float* __restrict__ Wih2, const float* __restrict__ Whh2,
    const float* __restrict__ bih2, const float* __restrict__ bhh2,
    const float* __restrict__ Wfc,  const float* __restrict__ bfc,
    const uint2* __restrict__ xw,
    float* __restrict__ out)
{
  constexpr int T = 1024, I = 32, H1 = 128, H2 = 64, BB = 16;
  constexpr int R1 = 272, R2 = 144;
  constexpr int H1_0 = 0, H1_1 = 4352;
  constexpr int H2_0 = 8704, H2_1 = 11008;
  constexpr int H2F  = 13312;
  __shared__ __align__(16) unsigned char smem[17408];

  const int tid  = threadIdx.x;
  const int w    = tid >> 6;
  const int lane = tid & 63;
  const int g    = lane >> 4;
  const int n    = lane & 15;
  const int b0   = blockIdx.x * BB;

  {
    uint32_t* p = (uint32_t*)smem;
    for (int i = tid; i < 1088; i += 512) p[i] = 0u;          // H1[0]
    uint32_t* q = (uint32_t*)(smem + H2_0);
    for (int i = tid; i < 576; i += 512) q[i] = 0u;           // H2[0]
  }

  int roff1[4];
#pragma unroll
  for (int k4 = 0; k4 < 4; ++k4)
    roff1[k4] = n * R1 + k4 * 64 + g * 16;

  auto tanh_pack = [&](const f32x4& a, uint32_t& lo, uint32_t& hi) {
    lo = pk16(tanh_fast(a[0]), tanh_fast(a[1]));
    hi = pk16(tanh_fast(a[2]), tanh_fast(a[3]));
  };

  __syncthreads();

  const f32x4 zero = {0.f, 0.f, 0.f, 0.f};

  if (w < 4) {
    // ===== layer-1 wave: tiles {2w, 2w+1} = channels 32w..32w+31 =====
    f16x8 aU[2][4];
#pragma unroll
    for (int ti = 0; ti < 2; ++ti) {
      const int ch = (2 * w + ti) * 16 + n;
#pragma unroll
      for (int k4 = 0; k4 < 4; ++k4)
        aU[ti][k4] = cvt8w(Whh1 + ch * H1 + k4 * 32 + g * 8);
    }
    int woff[2];
#pragma unroll
    for (int ti = 0; ti < 2; ++ti)
      woff[ti] = n * R1 + (2 * w + ti) * 32 + g * 8;

    if constexpr (USE_XW) {
      // -------- xw path: C-init from precomputed fp16 fragments --------
      const uint2* xwp = xw + (size_t)blockIdx.x * T * 512 + lane;
      const int ti0 = (2 * w) * 64, ti1 = (2 * w + 1) * 64;

      auto cvtC = [](uint2 v) -> f32x4 {
        f16x4 h = __builtin_bit_cast(f16x4, v);
        f32x4 r;
#pragma unroll
        for (int i = 0; i < 4; ++i) r[i] = (float)h[i];
        return r;
      };

      uint2 qA0 = xwp[0 * 512 + ti0], qA1 = xwp[0 * 512 + ti1];
      uint2 qB0 = xwp[1 * 512 + ti0], qB1 = xwp[1 * 512 + ti1];

      auto stepL1 = [&](int t, int cur, uint2& s0, uint2& s1) {
        const char* H1c = (const char*)smem + (cur ? H1_1 : H1_0);
        char*       H1n = (char*)smem + (cur ? H1_0 : H1_1);
        f16x8 b1k0 = *(const f16x8*)(H1c + roff1[0]);
        f16x8 b1k1 = *(const f16x8*)(H1c + roff1[1]);
        f16x8 b1k2 = *(const f16x8*)(H1c + roff1[2]);
        f16x8 b1k3 = *(const f16x8*)(H1c + roff1[3]);
        f32x4 accI0 = cvtC(s0), accI1 = cvtC(s1);
        if (t + 2 < T) {  // prefetch xw(t+2) into the just-consumed slots
          s0 = xwp[(t + 2) * 512 + ti0];
          s1 = xwp[(t + 2) * 512 + ti1];
        }
        f32x4 aA0 = MFMA_F16(aU[0][0], b1k0, accI0);
        f32x4 aB0 = MFMA_F16(aU[0][2], b1k2, zero);
        f32x4 aA1 = MFMA_F16(aU[1][0], b1k0, accI1);
        f32x4 aB1 = MFMA_F16(aU[1][2], b1k2, zero);
        aA0 = MFMA_F16(aU[0][1], b1k1, aA0);
        aB0 = MFMA_F16(aU[0][3], b1k3, aB0);
        aA1 = MFMA_F16(aU[1][1], b1k1, aA1);
        aB1 = MFMA_F16(aU[1][3], b1k3, aB1);
        {
          f32x4 s0v = aA0 + aB0;
          uint32_t lo, hi;
          tanh_pack(s0v, lo, hi);
          *(uint2*)(H1n + woff[0]) = make_uint2(lo, hi);
        }
        {
          f32x4 s1v = aA1 + aB1;
          uint32_t lo, hi;
          tanh_pack(s1v, lo, hi);
          *(uint2*)(H1n + woff[1]) = make_uint2(lo, hi);
        }
        sync_lds();
      };

      for (int t = 0; t < T; t += 2) {
        stepL1(t + 0, 0, qA0, qA1);
        stepL1(t + 1, 1, qB0, qB1);
      }
    } else {
      // -------- fallback: exact r4 x-path --------
      f16x8 aI1[2];
      f32x4 bias1[2];
#pragma unroll
      for (int ti = 0; ti < 2; ++ti) {
        const int ch = (2 * w + ti) * 16 + n;
        aI1[ti] = cvt8w(Wih1 + ch * I + g * 8);
        const int cb = (2 * w + ti) * 16 + g * 4;
#pragma unroll
        for (int r = 0; r < 4; ++r) bias1[ti][r] = bih1[cb + r] + bhh1[cb + r];
      }
      const float* xp = x + (size_t)(b0 + n) * T * I + g * 8;
      f32x4 q0a = *(const f32x4*)(xp + 0 * I), q0b = *(const f32x4*)(xp + 0 * I + 4);
      f32x4 q1a = *(const f32x4*)(xp + 1 * I), q1b = *(const f32x4*)(xp + 1 * I + 4);
      f32x4 q2a = *(const f32x4*)(xp + 2 * I), q2b = *(const f32x4*)(xp + 2 * I + 4);
      f32x4 q3a = *(const f32x4*)(xp + 3 * I), q3b = *(const f32x4*)(xp + 3 * I + 4);

      f32x4 accI0, accI1;
      {
        f16x8 xf = pack_x8(q0a, q0b);
        accI0 = MFMA_F16(aI1[0], xf, bias1[0]);
        accI1 = MFMA_F16(aI1[1], xf, bias1[1]);
      }

      auto stepL1 = [&](int t, int cur, f32x4& la, f32x4& lb,
                        const f32x4& pa, const f32x4& pb) {
        const char* H1c = (const char*)smem + (cur ? H1_1 : H1_0);
        char*       H1n = (char*)smem + (cur ? H1_0 : H1_1);
        f16x8 b1k0 = *(const f16x8*)(H1c + roff1[0]);
        f16x8 b1k1 = *(const f16x8*)(H1c + roff1[1]);
        f16x8 b1k2 = *(const f16x8*)(H1c + roff1[2]);
        f16x8 b1k3 = *(const f16x8*)(H1c + roff1[3]);
        if (t + 4 < T) {
          la = *(const f32x4*)(xp + (t + 4) * I);
          lb = *(const f32x4*)(xp + (t + 4) * I + 4);
        }
        f32x4 aA0 = MFMA_F16(aU[0][0], b1k0, accI0);
        f32x4 aB0 = MFMA_F16(aU[0][2], b1k2, zero);
        f32x4 aA1 = MFMA_F16(aU[1][0], b1k0, accI1);
        f32x4 aB1 = MFMA_F16(aU[1][2], b1k2, zero);
        aA0 = MFMA_F16(aU[0][1], b1k1, aA0);
        aB0 = MFMA_F16(aU[0][3], b1k3, aB0);
        aA1 = MFMA_F16(aU[1][1], b1k1, aA1);
        aB1 = MFMA_F16(aU[1][3], b1k3, aB1);
        {
          f16x8 xf = pack_x8(pa, pb);
          accI0 = MFMA_F16(aI1[0], xf, bias1[0]);
          accI1 = MFMA_F16(aI1[1], xf, bias1[1]);
        }
        {
          f32x4 s0 = aA0 + aB0;
          uint32_t lo, hi;
          tanh_pack(s0, lo, hi);
          *(uint2*)(H1n + woff[0]) = make_uint2(lo, hi);
        }
        {
          f32x4 s1 = aA1 + aB1;
          uint32_t lo, hi;
          tanh_pack(s1, lo, hi);
          *(uint2*)(H1n + woff[1]) = make_uint2(lo, hi);
        }
        sync_lds();
      };

      for (int t = 0; t < T; t += 4) {
        stepL1(t + 0, 0, q0a, q0b, q1a, q1b);
        stepL1(t + 1, 1, q1a, q1b, q2a, q2b);
        stepL1(t + 2, 0, q2a, q2b, q3a, q3b);
        stepL1(t + 3, 1, q3a, q3b, q0a, q0b);
      }
    }
  } else {
    // ===== layer-2 wave: tile j = w-4, channels 16j..16j+15 =====
    const int j = w - 4;
    f16x8 aI2[4], aR2[2];
#pragma unroll
    for (int k4 = 0; k4 < 4; ++k4)
      aI2[k4] = cvt8w(Wih2 + (16 * j + n) * H1 + k4 * 32 + g * 8);
#pragma unroll
    for (int k2 = 0; k2 < 2; ++k2)
      aR2[k2] = cvt8w(Whh2 + (16 * j + n) * H2 + k2 * 32 + g * 8);
    f32x4 bias2;
#pragma unroll
    for (int r = 0; r < 4; ++r) bias2[r] = bih2[16 * j + g * 4 + r] + bhh2[16 * j + g * 4 + r];

    int roff2[2];
#pragma unroll
    for (int k2 = 0; k2 < 2; ++k2)
      roff2[k2] = n * R2 + k2 * 64 + g * 16;
    const int woff2 = n * R2 + j * 32 + g * 8;

    auto l2_body = [&](const char* H1c, const char* H2r, f32x4& s) {
      f16x8 b1k0 = *(const f16x8*)(H1c + roff1[0]);
      f16x8 b1k1 = *(const f16x8*)(H1c + roff1[1]);
      f16x8 b1k2 = *(const f16x8*)(H1c + roff1[2]);
      f16x8 b1k3 = *(const f16x8*)(H1c + roff1[3]);
      f16x8 b2k0 = *(const f16x8*)(H2r + roff2[0]);
      f16x8 b2k1 = *(const f16x8*)(H2r + roff2[1]);
      f32x4 cA = MFMA_F16(aI2[0], b1k0, bias2);
      f32x4 cB = MFMA_F16(aI2[1], b1k1, zero);
      f32x4 cC = MFMA_F16(aR2[0], b2k0, zero);
      cA = MFMA_F16(aI2[2], b1k2, cA);
      cB = MFMA_F16(aI2[3], b1k3, cB);
      cC = MFMA_F16(aR2[1], b2k1, cC);
      s = cA + cB + cC;
    };

    auto stepL2 = [&](int t, int cur) {
      if (t > 0) {
        const char* H1c = (const char*)smem + (cur ? H1_1 : H1_0);   // h1(t)
        const char* H2r = (const char*)smem + (cur ? H2_0 : H2_1);   // h2(t-1)
        char*       H2w = (char*)smem + (cur ? H2_1 : H2_0);         // h2(t)
        f32x4 s;
        l2_body(H1c, H2r, s);
        uint32_t lo, hi;
        tanh_pack(s, lo, hi);
        *(uint2*)(H2w + woff2) = make_uint2(lo, hi);
      }
      sync_lds();
    };

    for (int t = 0; t < T; t += 2) {
      stepL2(t + 0, 0);
      stepL2(t + 1, 1);
    }

    // final: h2(T) from h1(T) [H1_0] and h2(T-1) [H2_1]
    {
      f32x4 s;
      l2_body((const char*)smem + H1_0, (const char*)smem + H2_1, s);
      f32x4 hv;
#pragma unroll
      for (int r = 0; r < 4; ++r) hv[r] = tanh_fast(s[r]);
      *(f32x4*)(smem + H2F + n * 256 + (16 * j + 4 * g) * 4) = hv;
    }
  }

  sync_lds();

  if (tid < BB * 10) {
    const int b = tid / 10, c = tid % 10;
    const float* hrow = (const float*)(smem + H2F + b * 256);
    float acc = bfc[c];
#pragma unroll 8
    for (int k = 0; k < 64; ++k) acc += hrow[k] * Wfc[c * 64 + k];
    out[(size_t)(b0 + b) * 10 + c] = acc;
  }
}

extern "C" void kernel_launch(void* const* d_in, const int* in_sizes, int n_in,
                              void* d_out, int out_size, void* d_ws, size_t ws_size,
                              hipStream_t stream) {
  const float* x    = (const float*)d_in[0];
  const float* Wih1 = (const float*)d_in[1];
  const float* Whh1 = (const float*)d_in[2];
  const float* bih1 = (const float*)d_in[3];
  const float* bhh1 = (const float*)d_in[4];
  const float* Wih2 = (const float*)d_in[5];
  const float* Whh2 = (const float*)d_in[6];
  const float* bih2 = (const float*)d_in[7];
  const float* bhh2 = (const float*)d_in[8];
  const float* Wfc  = (const float*)d_in[9];
  const float* bfc  = (const float*)d_in[10];

  const size_t xw_bytes = (size_t)512 * 1024 * 128 * 2;  // 134 MB fp16
  if (ws_size >= xw_bytes) {
    uint2* xw = (uint2*)d_ws;
    hipLaunchKernelGGL(xw_pre, dim3(256), dim3(256), 0, stream,
                       x, Wih1, bih1, bhh1, xw);
    hipLaunchKernelGGL((rnn_rec<true>), dim3(512 / 16), dim3(512), 0, stream,
                       x, Wih1, Whh1, bih1, bhh1, Wih2, Whh2, bih2, bhh2,
                       Wfc, bfc, (const uint2*)xw, (float*)d_out);
  } else {
    hipLaunchKernelGGL((rnn_rec<false>), dim3(512 / 16), dim3(512), 0, stream,
                       x, Wih1, Whh1, bih1, bhh1, Wih2, Whh2, bih2, bhh2,
                       Wfc, bfc, (const uint2*)nullptr, (float*)d_out);
  }
}